// Round 13
// baseline (260.915 us; speedup 1.0000x reference)
//
#include <hip/hip_runtime.h>
#include <math.h>

#define B_  2
#define T_  4096
#define D_  1024
#define H_  16
#define HD_ 64
#define M_  8192   // B*T

using f32x4  = __attribute__((ext_vector_type(4)))  float;
using f32x16 = __attribute__((ext_vector_type(16))) float;
using bfrag  = __attribute__((ext_vector_type(8)))  short;

__device__ __forceinline__ unsigned short f2bf(float f) {
  union { float f; unsigned u; } v; v.f = f;
  unsigned r = v.u + 0x7FFFu + ((v.u >> 16) & 1u);
  return (unsigned short)(r >> 16);
}

__device__ __forceinline__ unsigned cvt_pk(float lo, float hi) {
  unsigned r;
  asm("v_cvt_pk_bf16_f32 %0, %1, %2" : "=v"(r) : "v"(lo), "v"(hi));
  return r;
}

// a' = [a.lo32lanes, b.lo32lanes], b' = [a.hi32lanes, b.hi32lanes]
// NOTE: operands must be values the compiler cannot prove identical
// (same-value coalescing -> self-swap -> undefined result; R7 NaN).
__device__ __forceinline__ void plswap(unsigned &a, unsigned &b) {
  asm("v_permlane32_swap_b32 %0, %1" : "+v"(a), "+v"(b));
}

__device__ __forceinline__ void async16(const void* g, void* l) {
  __builtin_amdgcn_global_load_lds(
      (const __attribute__((address_space(1))) unsigned int*)g,
      (__attribute__((address_space(3))) unsigned int*)l, 16, 0, 0);
}

// bijective XCD swizzle for flat workgroup id (nwg must be divisible by 8)
__device__ __forceinline__ int xcd_swz(int flat, int nwg) {
  const int cpx = nwg >> 3;
  return (flat & 7) * cpx + (flat >> 3);
}

// ---------------------------------------------------------------------------
// fp32 -> bf16 conversion of x and the four weight matrices into ws
// ---------------------------------------------------------------------------
__global__ __launch_bounds__(256) void convert_all(
    const float* __restrict__ x, const float* __restrict__ wq,
    const float* __restrict__ wk, const float* __restrict__ wv,
    const float* __restrict__ wo, unsigned short* __restrict__ dst)
{
  const size_t NX = (size_t)M_ * D_ / 4;
  const size_t NW = (size_t)D_ * D_ / 4;
  const size_t total = NX + 4 * NW;
  size_t i = (size_t)blockIdx.x * blockDim.x + threadIdx.x;
  size_t stride = (size_t)gridDim.x * blockDim.x;
  for (size_t v = i; v < total; v += stride) {
    const float4* src;
    if (v < NX) {
      src = (const float4*)x + v;
    } else {
      size_t j = v - NX;
      const float* wp = (j < NW) ? wq : (j < 2*NW) ? wk : (j < 3*NW) ? wv : wo;
      src = (const float4*)wp + (j & (NW - 1));
    }
    float4 f = *src;
    ushort4 u;
    u.x = f2bf(f.x); u.y = f2bf(f.y); u.z = f2bf(f.z); u.w = f2bf(f.w);
    *(ushort4*)(dst + v * 4) = u;
  }
}

// ---------------------------------------------------------------------------
// Fused QKV projection: A[8192,1024] x W[3072,1024]^T  (W = wq|wk|wv).
// Q stored (b,h,t,d) bf16 (scaled). K and V stored FRAGMENT-MAJOR bf16:
// 512-element blocks, one per (tile j, khalf, slice); within a block,
// element for lane (l31, hi5), byte e sits at offset l31*16 + hi5*8 + e.
//   K block: ((bh*64 + j)*8 + khalf*4 + s)        with t=j*64+khalf*32+l31,
//                                                      d=s*16+hi5*8+e
//   V block: ((bh*64 + j)*8 + khalf*4 + S*2+dset) with t=j*64+khalf*32+S*16
//                                                        +hi5*8+e, d=dset*32+l31
// XCD-swizzled block mapping (nwg=1536 divisible by 8).
// ---------------------------------------------------------------------------
__global__ __launch_bounds__(256) void gemm_qkv(
    const unsigned short* __restrict__ A,
    const unsigned short* __restrict__ Ww,
    const float* __restrict__ bq, const float* __restrict__ bk,
    const float* __restrict__ bv,
    unsigned short* __restrict__ Qb, unsigned short* __restrict__ Kb,
    unsigned short* __restrict__ Vtb, float qscale)
{
  __shared__ unsigned short a_t[128 * 64];
  __shared__ unsigned short b_t[128 * 64];
  const int tid = threadIdx.x;
  const int lane = tid & 63;
  const int w = tid >> 6;
  const int lo = lane & 15, hi = lane >> 4;
  const int swz = xcd_swz(blockIdx.y * gridDim.x + blockIdx.x,
                          gridDim.x * gridDim.y);
  const int mbase = (swz % gridDim.x) * 128;
  const int nbase = (swz / gridDim.x) * 128;
  const int wm = w >> 1, wn = w & 1;
  const int K = D_;

  f32x4 acc[4][4];
  #pragma unroll
  for (int m = 0; m < 4; m++)
    #pragma unroll
    for (int n = 0; n < 4; n++) acc[m][n] = f32x4{0.f, 0.f, 0.f, 0.f};

  for (int k0 = 0; k0 < K; k0 += 64) {
    #pragma unroll
    for (int i = 0; i < 4; i++) {
      const int cb = i * 256 + w * 64;
      const int chunk = cb + lane;
      const int row = chunk >> 3, c8 = chunk & 7;
      async16(A  + (size_t)(mbase + row) * K + k0 + c8 * 8, &a_t[cb * 8]);
      async16(Ww + (size_t)(nbase + row) * K + k0 + c8 * 8, &b_t[cb * 8]);
    }
    __syncthreads();
    #pragma unroll
    for (int kk = 0; kk < 2; kk++) {
      bfrag af[4], bf[4];
      #pragma unroll
      for (int m = 0; m < 4; m++)
        af[m] = *(const bfrag*)&a_t[(wm * 64 + m * 16 + lo) * 64 + kk * 32 + hi * 8];
      #pragma unroll
      for (int n = 0; n < 4; n++)
        bf[n] = *(const bfrag*)&b_t[(wn * 64 + n * 16 + lo) * 64 + kk * 32 + hi * 8];
      #pragma unroll
      for (int m = 0; m < 4; m++)
        #pragma unroll
        for (int n = 0; n < 4; n++)
          acc[m][n] = __builtin_amdgcn_mfma_f32_16x16x32_bf16(af[m], bf[n], acc[m][n], 0, 0, 0);
    }
    __syncthreads();
  }

  const int which = nbase >> 10;                    // 0=Q 1=K 2=V
  const float* bias = (which == 0) ? bq : (which == 1) ? bk : bv;
  const float osc = (which == 0) ? qscale : 1.0f;
  const int nloc = nbase & 1023;

  float bvv[4];
  #pragma unroll
  for (int n = 0; n < 4; n++) bvv[n] = bias[nloc + wn * 64 + n * 16 + lo];

  #pragma unroll
  for (int m = 0; m < 4; m++) {
    const int rowl = wm * 64 + m * 16 + hi * 4;
    #pragma unroll
    for (int n = 0; n < 4; n++) {
      const int gn = nloc + wn * 64 + n * 16 + lo;
      const int h = gn >> 6, d = gn & 63;
      #pragma unroll
      for (int i = 0; i < 4; i++) {
        const float v = (acc[m][n][i] + bvv[n]) * osc;
        const int gm = mbase + rowl + i;
        const int b = gm >> 12, t = gm & 4095;
        const int bh = b * H_ + h;
        if (which == 0) {
          Qb[(((size_t)bh * T_) + t) * HD_ + d] = f2bf(v);
        } else if (which == 1) {
          const int j = t >> 6, kh = (t >> 5) & 1, l31r = t & 31;
          const int s = d >> 4, h5 = (d >> 3) & 1, e = d & 7;
          Kb[(((size_t)(bh * 64 + j) * 8 + kh * 4 + s) * 512)
             + l31r * 16 + h5 * 8 + e] = f2bf(v);
        } else {
          const int j = t >> 6, kh = (t >> 5) & 1, S = (t >> 4) & 1;
          const int h5 = (t >> 3) & 1, e = t & 7;
          const int dset = d >> 5, l31r = d & 31;
          Vtb[(((size_t)(bh * 64 + j) * 8 + kh * 4 + S * 2 + dset) * 512)
              + l31r * 16 + h5 * 8 + e] = f2bf(v);
        }
      }
    }
  }
}

// ---------------------------------------------------------------------------
// Output projection: C = A(MxK bf16) * B(NxK bf16)^T + bias -> f32 (m,n)
// XCD-swizzled block mapping (nwg=512 divisible by 8).
// ---------------------------------------------------------------------------
__global__ __launch_bounds__(256) void gemm_out(
    const unsigned short* __restrict__ A,
    const unsigned short* __restrict__ Bw,
    const float* __restrict__ bias,
    float* __restrict__ out,
    int M, int N, int K)
{
  __shared__ unsigned short a_t[128 * 64];
  __shared__ unsigned short b_t[128 * 64];
  const int tid = threadIdx.x;
  const int lane = tid & 63;
  const int w = tid >> 6;
  const int lo = lane & 15, hi = lane >> 4;
  const int swz = xcd_swz(blockIdx.y * gridDim.x + blockIdx.x,
                          gridDim.x * gridDim.y);
  const int mbase = (swz % gridDim.x) * 128;
  const int nbase = (swz / gridDim.x) * 128;
  const int wm = w >> 1, wn = w & 1;

  f32x4 acc[4][4];
  #pragma unroll
  for (int m = 0; m < 4; m++)
    #pragma unroll
    for (int n = 0; n < 4; n++) acc[m][n] = f32x4{0.f, 0.f, 0.f, 0.f};

  for (int k0 = 0; k0 < K; k0 += 64) {
    #pragma unroll
    for (int i = 0; i < 4; i++) {
      const int cb = i * 256 + w * 64;
      const int chunk = cb + lane;
      const int row = chunk >> 3, c8 = chunk & 7;
      async16(A  + (size_t)(mbase + row) * K + k0 + c8 * 8, &a_t[cb * 8]);
      async16(Bw + (size_t)(nbase + row) * K + k0 + c8 * 8, &b_t[cb * 8]);
    }
    __syncthreads();
    #pragma unroll
    for (int kk = 0; kk < 2; kk++) {
      bfrag af[4], bf[4];
      #pragma unroll
      for (int m = 0; m < 4; m++)
        af[m] = *(const bfrag*)&a_t[(wm * 64 + m * 16 + lo) * 64 + kk * 32 + hi * 8];
      #pragma unroll
      for (int n = 0; n < 4; n++)
        bf[n] = *(const bfrag*)&b_t[(wn * 64 + n * 16 + lo) * 64 + kk * 32 + hi * 8];
      #pragma unroll
      for (int m = 0; m < 4; m++)
        #pragma unroll
        for (int n = 0; n < 4; n++)
          acc[m][n] = __builtin_amdgcn_mfma_f32_16x16x32_bf16(af[m], bf[n], acc[m][n], 0, 0, 0);
    }
    __syncthreads();
  }

  float bvv[4];
  #pragma unroll
  for (int n = 0; n < 4; n++) bvv[n] = bias[nbase + wn * 64 + n * 16 + lo];

  #pragma unroll
  for (int m = 0; m < 4; m++) {
    const int rowl = wm * 64 + m * 16 + hi * 4;
    #pragma unroll
    for (int n = 0; n < 4; n++) {
      const int gn = nbase + wn * 64 + n * 16 + lo;
      #pragma unroll
      for (int i = 0; i < 4; i++)
        out[(size_t)(mbase + rowl + i) * N + gn] = acc[m][n][i] + bvv[n];
    }
  }
}

// ---------------------------------------------------------------------------
// Causal flash attention, barrier-free with FRAGMENT-MAJOR K/V.
// Fragment loads: 64 lanes x 16B = one contiguous 1KB block per fragment
// (intra-block order l31*16 + hi5*8, matching gemm_qkv's store).
// No LDS staging, no main-loop barriers. SINGLE K register set: kA is
// reloaded in place immediately after the 4 QK MFMAs consume it (the load
// retires under the ~400-cycle softmax+PV tail -> prefetch preserved at
// -16 arch regs). V loaded at iteration top, consumed at PV.
// REGISTER BUDGET (R6/R11 lessons): launch_bounds 2nd arg caps COMBINED
// arch+acc regs at 512/N. Here: ~60 arch + 48 acc (o0,o1,st) ~= 108 -> N=4
// (cap 128) for 4 waves/SIMD; R12 at N=3 measured 30% occupancy, VALU 68%.
// Grid: 2048 = 32 bh x 64 q-groups (64 rows, heavy first).
// wave w: qhalf = w>>1, khalf = w&1; partner waves merge O/l via small LDS.
// Shift-free softmax (p = exp2(S), Q pre-scaled by 1/sqrt(hd)*log2e).
// S^T = mfma32(K, Q): lane owns q-col = lane&31; k per reg r:
// k = 32*khalf + (r&3)+8*(r>>2)+4*(lane>>5). P->bf16 via cvt_pk+permlane32;
// O^T = mfma32(V^T, P^T).
// ---------------------------------------------------------------------------
__global__ __launch_bounds__(256, 4) void attn_kernel(
    const unsigned short* __restrict__ Qg,
    const unsigned short* __restrict__ Kf,
    const unsigned short* __restrict__ Vf,
    unsigned short* __restrict__ Og)
{
  __shared__ float smrg[2176];                 // merge scratch (8.7 KB)
  const int tid = threadIdx.x, lane = tid & 63, w = tid >> 6;
  const int l31 = lane & 31, hi5 = lane >> 5;
  const int bh = blockIdx.x & 31;
  const int qgroup = 63 - (blockIdx.x >> 5);   // heavy groups first
  const int qhalf = w >> 1, khalf = w & 1;
  const int a = qgroup * 2 + qhalf;            // 32-row q-subtile index
  const int qg_lane = qgroup * 64 + qhalf * 32 + l31;
  const int jw = (a >= khalf) ? ((a - khalf) >> 1) : -1;  // last computed tile
  const int b = bh >> 4, h = bh & 15;

  // Q B-fragments (hd slice s at +s*16)
  bfrag qf0, qf1, qf2, qf3;
  {
    const unsigned short* qp = Qg + ((size_t)bh * T_ + qg_lane) * HD_ + hi5 * 8;
    qf0 = *(const bfrag*)(qp);
    qf1 = *(const bfrag*)(qp + 16);
    qf2 = *(const bfrag*)(qp + 32);
    qf3 = *(const bfrag*)(qp + 48);
  }

  // fragment-major pointers: tile j at +j*4096; K slice s at +s*512;
  // V (S,dset) at +(S*2+dset)*512; intra-block lane offset l31*16 + hi5*8.
  const int loff = l31 * 16 + hi5 * 8;
  const unsigned short* kp =
      Kf + ((size_t)(bh * 64) * 8 + khalf * 4) * 512 + loff;
  const unsigned short* vp =
      Vf + ((size_t)(bh * 64) * 8 + khalf * 4) * 512 + loff;

  f32x16 o0, o1;
  #pragma unroll
  for (int r = 0; r < 16; r++) { o0[r] = 0.f; o1[r] = 0.f; }
  float l = 0.f;

  bfrag kA0, kA1, kA2, kA3;
  bfrag vf00, vf01, vf10, vf11;   // [S][dset]

  #define LOADK() do {                                                       \
    kA0 = *(const bfrag*)(kp);                                               \
    kA1 = *(const bfrag*)(kp + 512);                                         \
    kA2 = *(const bfrag*)(kp + 1024);                                        \
    kA3 = *(const bfrag*)(kp + 1536);                                        \
    kp += 4096;                                                              \
  } while (0)

  #define LOADV() do {                                                       \
    vf00 = *(const bfrag*)(vp);                                              \
    vf01 = *(const bfrag*)(vp + 512);                                        \
    vf10 = *(const bfrag*)(vp + 1024);                                       \
    vf11 = *(const bfrag*)(vp + 1536);                                       \
    vp += 4096;                                                              \
  } while (0)

  if (jw >= 0) {
    LOADK();                        // tile 0
    for (int j = 0; j <= jw; ++j) {
      LOADV();                      // V tile j (consumed at PV below)

      // ---- S^T subtile = K[khalf] * Q^T over hd=64
      f32x16 st;
      #pragma unroll
      for (int r = 0; r < 16; r++) st[r] = 0.f;
      __builtin_amdgcn_s_setprio(1);
      st = __builtin_amdgcn_mfma_f32_32x32x16_bf16(kA0, qf0, st, 0, 0, 0);
      st = __builtin_amdgcn_mfma_f32_32x32x16_bf16(kA1, qf1, st, 0, 0, 0);
      st = __builtin_amdgcn_mfma_f32_32x32x16_bf16(kA2, qf2, st, 0, 0, 0);
      st = __builtin_amdgcn_mfma_f32_32x32x16_bf16(kA3, qf3, st, 0, 0, 0);
      __builtin_amdgcn_s_setprio(0);

      // prefetch K tile j+1 in place (retires under softmax+PV below)
      if (j < jw) LOADK();

      // ---- causal mask (only the wave's last tile can be diagonal)
      if (j == jw) {
        const int thr = qg_lane - 64 * j - 32 * khalf - 4 * hi5;
        #pragma unroll
        for (int r = 0; r < 16; r++) {
          const int kl = (r & 3) + 8 * (r >> 2);
          st[r] = (kl > thr) ? -INFINITY : st[r];
        }
      }

      // ---- p = exp2(S) (shift-free), partial row-sum
      #pragma unroll
      for (int r = 0; r < 16; r++) st[r] = exp2f(st[r]);
      {
        float s8[8];
        #pragma unroll
        for (int r = 0; r < 8; r++) s8[r] = st[r] + st[r + 8];
        float rs = ((s8[0] + s8[4]) + (s8[1] + s8[5])) +
                   ((s8[2] + s8[6]) + (s8[3] + s8[7]));
        rs += __shfl_xor(rs, 32);
        l += rs;
      }

      // ---- O^T += V^T * P^T
      {
        unsigned pk0 = cvt_pk(st[0], st[1]);
        unsigned pk1 = cvt_pk(st[2], st[3]);
        unsigned pk2 = cvt_pk(st[4], st[5]);
        unsigned pk3 = cvt_pk(st[6], st[7]);
        plswap(pk0, pk2);
        plswap(pk1, pk3);
        union { unsigned u[4]; bfrag f; } pb;
        pb.u[0] = pk0; pb.u[1] = pk1; pb.u[2] = pk2; pb.u[3] = pk3;
        __builtin_amdgcn_s_setprio(1);
        o0 = __builtin_amdgcn_mfma_f32_32x32x16_bf16(vf00, pb.f, o0, 0, 0, 0);
        o1 = __builtin_amdgcn_mfma_f32_32x32x16_bf16(vf01, pb.f, o1, 0, 0, 0);
        __builtin_amdgcn_s_setprio(0);
        pk0 = cvt_pk(st[8], st[9]);
        pk1 = cvt_pk(st[10], st[11]);
        pk2 = cvt_pk(st[12], st[13]);
        pk3 = cvt_pk(st[14], st[15]);
        plswap(pk0, pk2);
        plswap(pk1, pk3);
        pb.u[0] = pk0; pb.u[1] = pk1; pb.u[2] = pk2; pb.u[3] = pk3;
        __builtin_amdgcn_s_setprio(1);
        o0 = __builtin_amdgcn_mfma_f32_32x32x16_bf16(vf10, pb.f, o0, 0, 0, 0);
        o1 = __builtin_amdgcn_mfma_f32_32x32x16_bf16(vf11, pb.f, o1, 0, 0, 0);
        __builtin_amdgcn_s_setprio(0);
      }
    }
  }
  #undef LOADK
  #undef LOADV

  // ---- partner-wave (khalf) reduction via LDS, stride 17 (conflict-free)
  const int moff = (qhalf * 64 + lane) * 17;
  if (khalf) {
    #pragma unroll
    for (int r = 0; r < 16; r++) smrg[moff + r] = o0[r];
    smrg[moff + 16] = l;
  }
  __syncthreads();
  if (!khalf) {
    #pragma unroll
    for (int r = 0; r < 16; r++) o0[r] += smrg[moff + r];
    l += smrg[moff + 16];
  }
  __syncthreads();
  if (khalf) {
    #pragma unroll
    for (int r = 0; r < 16; r++) smrg[moff + r] = o1[r];
  }
  __syncthreads();
  if (!khalf) {
    #pragma unroll
    for (int r = 0; r < 16; r++) o1[r] += smrg[moff + r];
    const float inv = 1.0f / l;
    unsigned short* orow = Og + ((size_t)(b * T_ + qg_lane)) * D_ + h * HD_;
    #pragma unroll
    for (int r = 0; r < 16; r += 2) {
      const int d0 = (r & 3) + 8 * (r >> 2) + 4 * hi5;
      unsigned u0 = cvt_pk(o0[r] * inv, o0[r + 1] * inv);
      unsigned u1 = cvt_pk(o1[r] * inv, o1[r + 1] * inv);
      *(unsigned*)(orow + d0)      = u0;
      *(unsigned*)(orow + 32 + d0) = u1;
    }
  }
}

// ---------------------------------------------------------------------------
extern "C" void kernel_launch(void* const* d_in, const int* in_sizes, int n_in,
                              void* d_out, int out_size, void* d_ws, size_t ws_size,
                              hipStream_t stream)
{
  const float* x  = (const float*)d_in[0];
  const float* Wq = (const float*)d_in[1];
  const float* bq = (const float*)d_in[2];
  const float* Wk = (const float*)d_in[3];
  const float* bk = (const float*)d_in[4];
  const float* Wv = (const float*)d_in[5];
  const float* bv = (const float*)d_in[6];
  const float* Wo = (const float*)d_in[7];
  const float* bo = (const float*)d_in[8];

  unsigned short* ws  = (unsigned short*)d_ws;
  unsigned short* xb  = ws;
  unsigned short* wqb = xb  + (size_t)M_ * D_;     // wq|wk|wv contiguous
  unsigned short* wkb = wqb + (size_t)D_ * D_;
  unsigned short* wvb = wkb + (size_t)D_ * D_;
  unsigned short* wob = wvb + (size_t)D_ * D_;
  unsigned short* Qb  = wob + (size_t)D_ * D_;
  unsigned short* Kb  = Qb  + (size_t)M_ * D_;     // fragment-major
  unsigned short* Vtb = Kb  + (size_t)M_ * D_;     // fragment-major
  unsigned short* AOb = Vtb + (size_t)M_ * D_;

  convert_all<<<2048, 256, 0, stream>>>(x, Wq, Wk, Wv, Wo, xb);

  const float qscale = 0.125f * 1.44269504f;   // 1/sqrt(64) * log2(e)
  dim3 gq(M_ / 128, 3072 / 128);
  gemm_qkv<<<gq, 256, 0, stream>>>(xb, wqb, bq, bk, bv, Qb, Kb, Vtb, qscale);

  attn_kernel<<<2048, 256, 0, stream>>>(Qb, Kb, Vtb, AOb);

  dim3 go(M_ / 128, D_ / 128);
  gemm_out<<<go, 256, 0, stream>>>(AOb, wob, bo, (float*)d_out, M_, D_, D_);
}

// Round 14
// 236.404 us; speedup vs baseline: 1.1037x; 1.1037x over previous
//
#include <hip/hip_runtime.h>
#include <math.h>

#define B_  2
#define T_  4096
#define D_  1024
#define H_  16
#define HD_ 64
#define M_  8192   // B*T

using f32x4  = __attribute__((ext_vector_type(4)))  float;
using f32x16 = __attribute__((ext_vector_type(16))) float;
using bfrag  = __attribute__((ext_vector_type(8)))  short;

__device__ __forceinline__ unsigned short f2bf(float f) {
  union { float f; unsigned u; } v; v.f = f;
  unsigned r = v.u + 0x7FFFu + ((v.u >> 16) & 1u);
  return (unsigned short)(r >> 16);
}

__device__ __forceinline__ unsigned cvt_pk(float lo, float hi) {
  unsigned r;
  asm("v_cvt_pk_bf16_f32 %0, %1, %2" : "=v"(r) : "v"(lo), "v"(hi));
  return r;
}

// a' = [a.lo32lanes, b.lo32lanes], b' = [a.hi32lanes, b.hi32lanes]
// NOTE: operands must be values the compiler cannot prove identical
// (same-value coalescing -> self-swap -> undefined result; R7 NaN).
__device__ __forceinline__ void plswap(unsigned &a, unsigned &b) {
  asm("v_permlane32_swap_b32 %0, %1" : "+v"(a), "+v"(b));
}

__device__ __forceinline__ void async16(const void* g, void* l) {
  __builtin_amdgcn_global_load_lds(
      (const __attribute__((address_space(1))) unsigned int*)g,
      (__attribute__((address_space(3))) unsigned int*)l, 16, 0, 0);
}

// NOTE (R13 lesson): do NOT XCD-swizzle these GEMM grids. With m-tiles = 64
// (x fast-varying, 64 % 8 == 0) the default round-robin dispatch already
// gives each XCD a fixed m-slice (2 MB of A, L2-resident, reused across all
// n-panels). A contiguous-chunk swizzle gave each XCD the FULL 16 MB A
// working set -> FETCH 199 MB, gemm_qkv 60 -> 126 us.

// ---------------------------------------------------------------------------
// fp32 -> bf16 conversion of x and the four weight matrices into ws
// ---------------------------------------------------------------------------
__global__ __launch_bounds__(256) void convert_all(
    const float* __restrict__ x, const float* __restrict__ wq,
    const float* __restrict__ wk, const float* __restrict__ wv,
    const float* __restrict__ wo, unsigned short* __restrict__ dst)
{
  const size_t NX = (size_t)M_ * D_ / 4;
  const size_t NW = (size_t)D_ * D_ / 4;
  const size_t total = NX + 4 * NW;
  size_t i = (size_t)blockIdx.x * blockDim.x + threadIdx.x;
  size_t stride = (size_t)gridDim.x * blockDim.x;
  for (size_t v = i; v < total; v += stride) {
    const float4* src;
    if (v < NX) {
      src = (const float4*)x + v;
    } else {
      size_t j = v - NX;
      const float* wp = (j < NW) ? wq : (j < 2*NW) ? wk : (j < 3*NW) ? wv : wo;
      src = (const float4*)wp + (j & (NW - 1));
    }
    float4 f = *src;
    ushort4 u;
    u.x = f2bf(f.x); u.y = f2bf(f.y); u.z = f2bf(f.z); u.w = f2bf(f.w);
    *(ushort4*)(dst + v * 4) = u;
  }
}

// ---------------------------------------------------------------------------
// Fused QKV projection: A[8192,1024] x W[3072,1024]^T  (W = wq|wk|wv).
// Q stored (b,h,t,d) bf16 (scaled). K and V stored FRAGMENT-MAJOR bf16:
// 512-element blocks, one per (tile j, khalf, slice); within a block,
// element for lane (l31, hi5), byte e sits at offset l31*16 + hi5*8 + e.
//   K block: ((bh*64 + j)*8 + khalf*4 + s)        with t=j*64+khalf*32+l31,
//                                                      d=s*16+hi5*8+e
//   V block: ((bh*64 + j)*8 + khalf*4 + S*2+dset) with t=j*64+khalf*32+S*16
//                                                        +hi5*8+e, d=dset*32+l31
// ---------------------------------------------------------------------------
__global__ __launch_bounds__(256) void gemm_qkv(
    const unsigned short* __restrict__ A,
    const unsigned short* __restrict__ Ww,
    const float* __restrict__ bq, const float* __restrict__ bk,
    const float* __restrict__ bv,
    unsigned short* __restrict__ Qb, unsigned short* __restrict__ Kb,
    unsigned short* __restrict__ Vtb, float qscale)
{
  __shared__ unsigned short a_t[128 * 64];
  __shared__ unsigned short b_t[128 * 64];
  const int tid = threadIdx.x;
  const int lane = tid & 63;
  const int w = tid >> 6;
  const int lo = lane & 15, hi = lane >> 4;
  const int mbase = blockIdx.x * 128;
  const int nbase = blockIdx.y * 128;
  const int wm = w >> 1, wn = w & 1;
  const int K = D_;

  f32x4 acc[4][4];
  #pragma unroll
  for (int m = 0; m < 4; m++)
    #pragma unroll
    for (int n = 0; n < 4; n++) acc[m][n] = f32x4{0.f, 0.f, 0.f, 0.f};

  for (int k0 = 0; k0 < K; k0 += 64) {
    #pragma unroll
    for (int i = 0; i < 4; i++) {
      const int cb = i * 256 + w * 64;
      const int chunk = cb + lane;
      const int row = chunk >> 3, c8 = chunk & 7;
      async16(A  + (size_t)(mbase + row) * K + k0 + c8 * 8, &a_t[cb * 8]);
      async16(Ww + (size_t)(nbase + row) * K + k0 + c8 * 8, &b_t[cb * 8]);
    }
    __syncthreads();
    #pragma unroll
    for (int kk = 0; kk < 2; kk++) {
      bfrag af[4], bf[4];
      #pragma unroll
      for (int m = 0; m < 4; m++)
        af[m] = *(const bfrag*)&a_t[(wm * 64 + m * 16 + lo) * 64 + kk * 32 + hi * 8];
      #pragma unroll
      for (int n = 0; n < 4; n++)
        bf[n] = *(const bfrag*)&b_t[(wn * 64 + n * 16 + lo) * 64 + kk * 32 + hi * 8];
      #pragma unroll
      for (int m = 0; m < 4; m++)
        #pragma unroll
        for (int n = 0; n < 4; n++)
          acc[m][n] = __builtin_amdgcn_mfma_f32_16x16x32_bf16(af[m], bf[n], acc[m][n], 0, 0, 0);
    }
    __syncthreads();
  }

  const int which = nbase >> 10;                    // 0=Q 1=K 2=V
  const float* bias = (which == 0) ? bq : (which == 1) ? bk : bv;
  const float osc = (which == 0) ? qscale : 1.0f;
  const int nloc = nbase & 1023;

  float bvv[4];
  #pragma unroll
  for (int n = 0; n < 4; n++) bvv[n] = bias[nloc + wn * 64 + n * 16 + lo];

  #pragma unroll
  for (int m = 0; m < 4; m++) {
    const int rowl = wm * 64 + m * 16 + hi * 4;
    #pragma unroll
    for (int n = 0; n < 4; n++) {
      const int gn = nloc + wn * 64 + n * 16 + lo;
      const int h = gn >> 6, d = gn & 63;
      #pragma unroll
      for (int i = 0; i < 4; i++) {
        const float v = (acc[m][n][i] + bvv[n]) * osc;
        const int gm = mbase + rowl + i;
        const int b = gm >> 12, t = gm & 4095;
        const int bh = b * H_ + h;
        if (which == 0) {
          Qb[(((size_t)bh * T_) + t) * HD_ + d] = f2bf(v);
        } else if (which == 1) {
          const int j = t >> 6, kh = (t >> 5) & 1, l31r = t & 31;
          const int s = d >> 4, h5 = (d >> 3) & 1, e = d & 7;
          Kb[(((size_t)(bh * 64 + j) * 8 + kh * 4 + s) * 512)
             + l31r * 16 + h5 * 8 + e] = f2bf(v);
        } else {
          const int j = t >> 6, kh = (t >> 5) & 1, S = (t >> 4) & 1;
          const int h5 = (t >> 3) & 1, e = t & 7;
          const int dset = d >> 5, l31r = d & 31;
          Vtb[(((size_t)(bh * 64 + j) * 8 + kh * 4 + S * 2 + dset) * 512)
              + l31r * 16 + h5 * 8 + e] = f2bf(v);
        }
      }
    }
  }
}

// ---------------------------------------------------------------------------
// Output projection: C = A(MxK bf16) * B(NxK bf16)^T + bias -> f32 (m,n)
// ---------------------------------------------------------------------------
__global__ __launch_bounds__(256) void gemm_out(
    const unsigned short* __restrict__ A,
    const unsigned short* __restrict__ Bw,
    const float* __restrict__ bias,
    float* __restrict__ out,
    int M, int N, int K)
{
  __shared__ unsigned short a_t[128 * 64];
  __shared__ unsigned short b_t[128 * 64];
  const int tid = threadIdx.x;
  const int lane = tid & 63;
  const int w = tid >> 6;
  const int lo = lane & 15, hi = lane >> 4;
  const int mbase = blockIdx.x * 128;
  const int nbase = blockIdx.y * 128;
  const int wm = w >> 1, wn = w & 1;

  f32x4 acc[4][4];
  #pragma unroll
  for (int m = 0; m < 4; m++)
    #pragma unroll
    for (int n = 0; n < 4; n++) acc[m][n] = f32x4{0.f, 0.f, 0.f, 0.f};

  for (int k0 = 0; k0 < K; k0 += 64) {
    #pragma unroll
    for (int i = 0; i < 4; i++) {
      const int cb = i * 256 + w * 64;
      const int chunk = cb + lane;
      const int row = chunk >> 3, c8 = chunk & 7;
      async16(A  + (size_t)(mbase + row) * K + k0 + c8 * 8, &a_t[cb * 8]);
      async16(Bw + (size_t)(nbase + row) * K + k0 + c8 * 8, &b_t[cb * 8]);
    }
    __syncthreads();
    #pragma unroll
    for (int kk = 0; kk < 2; kk++) {
      bfrag af[4], bf[4];
      #pragma unroll
      for (int m = 0; m < 4; m++)
        af[m] = *(const bfrag*)&a_t[(wm * 64 + m * 16 + lo) * 64 + kk * 32 + hi * 8];
      #pragma unroll
      for (int n = 0; n < 4; n++)
        bf[n] = *(const bfrag*)&b_t[(wn * 64 + n * 16 + lo) * 64 + kk * 32 + hi * 8];
      #pragma unroll
      for (int m = 0; m < 4; m++)
        #pragma unroll
        for (int n = 0; n < 4; n++)
          acc[m][n] = __builtin_amdgcn_mfma_f32_16x16x32_bf16(af[m], bf[n], acc[m][n], 0, 0, 0);
    }
    __syncthreads();
  }

  float bvv[4];
  #pragma unroll
  for (int n = 0; n < 4; n++) bvv[n] = bias[nbase + wn * 64 + n * 16 + lo];

  #pragma unroll
  for (int m = 0; m < 4; m++) {
    const int rowl = wm * 64 + m * 16 + hi * 4;
    #pragma unroll
    for (int n = 0; n < 4; n++) {
      const int gn = nbase + wn * 64 + n * 16 + lo;
      #pragma unroll
      for (int i = 0; i < 4; i++)
        out[(size_t)(mbase + rowl + i) * N + gn] = acc[m][n][i] + bvv[n];
    }
  }
}

// ---------------------------------------------------------------------------
// Causal flash attention, barrier-free with FRAGMENT-MAJOR K/V.
// Fragment loads: 64 lanes x 16B = one contiguous 1KB block per fragment
// (intra-block order l31*16 + hi5*8, matching gemm_qkv's store).
// No LDS staging, no main-loop barriers. SINGLE K register set: kA is
// reloaded in place immediately after the 4 QK MFMAs consume it (the load
// retires under the ~400-cycle softmax+PV tail -> prefetch preserved at
// -16 arch regs). V loaded at iteration top, consumed at PV.
// REGISTER BUDGET (R6/R11 lessons): launch_bounds 2nd arg caps COMBINED
// arch+acc regs at 512/N. Here: ~60 arch + 48 acc (o0,o1,st) ~= 108 -> N=4
// (cap 128) for 4 waves/SIMD.
// Grid: 2048 = 32 bh x 64 q-groups (64 rows, heavy first).
// wave w: qhalf = w>>1, khalf = w&1; partner waves merge O/l via small LDS.
// Shift-free softmax (p = exp2(S), Q pre-scaled by 1/sqrt(hd)*log2e).
// S^T = mfma32(K, Q): lane owns q-col = lane&31; k per reg r:
// k = 32*khalf + (r&3)+8*(r>>2)+4*(lane>>5). P->bf16 via cvt_pk+permlane32;
// O^T = mfma32(V^T, P^T).
// ---------------------------------------------------------------------------
__global__ __launch_bounds__(256, 4) void attn_kernel(
    const unsigned short* __restrict__ Qg,
    const unsigned short* __restrict__ Kf,
    const unsigned short* __restrict__ Vf,
    unsigned short* __restrict__ Og)
{
  __shared__ float smrg[2176];                 // merge scratch (8.7 KB)
  const int tid = threadIdx.x, lane = tid & 63, w = tid >> 6;
  const int l31 = lane & 31, hi5 = lane >> 5;
  const int bh = blockIdx.x & 31;
  const int qgroup = 63 - (blockIdx.x >> 5);   // heavy groups first
  const int qhalf = w >> 1, khalf = w & 1;
  const int a = qgroup * 2 + qhalf;            // 32-row q-subtile index
  const int qg_lane = qgroup * 64 + qhalf * 32 + l31;
  const int jw = (a >= khalf) ? ((a - khalf) >> 1) : -1;  // last computed tile
  const int b = bh >> 4, h = bh & 15;

  // Q B-fragments (hd slice s at +s*16)
  bfrag qf0, qf1, qf2, qf3;
  {
    const unsigned short* qp = Qg + ((size_t)bh * T_ + qg_lane) * HD_ + hi5 * 8;
    qf0 = *(const bfrag*)(qp);
    qf1 = *(const bfrag*)(qp + 16);
    qf2 = *(const bfrag*)(qp + 32);
    qf3 = *(const bfrag*)(qp + 48);
  }

  // fragment-major pointers: tile j at +j*4096; K slice s at +s*512;
  // V (S,dset) at +(S*2+dset)*512; intra-block lane offset l31*16 + hi5*8.
  const int loff = l31 * 16 + hi5 * 8;
  const unsigned short* kp =
      Kf + ((size_t)(bh * 64) * 8 + khalf * 4) * 512 + loff;
  const unsigned short* vp =
      Vf + ((size_t)(bh * 64) * 8 + khalf * 4) * 512 + loff;

  f32x16 o0, o1;
  #pragma unroll
  for (int r = 0; r < 16; r++) { o0[r] = 0.f; o1[r] = 0.f; }
  float l = 0.f;

  bfrag kA0, kA1, kA2, kA3;
  bfrag vf00, vf01, vf10, vf11;   // [S][dset]

  #define LOADK() do {                                                       \
    kA0 = *(const bfrag*)(kp);                                               \
    kA1 = *(const bfrag*)(kp + 512);                                         \
    kA2 = *(const bfrag*)(kp + 1024);                                        \
    kA3 = *(const bfrag*)(kp + 1536);                                        \
    kp += 4096;                                                              \
  } while (0)

  #define LOADV() do {                                                       \
    vf00 = *(const bfrag*)(vp);                                              \
    vf01 = *(const bfrag*)(vp + 512);                                        \
    vf10 = *(const bfrag*)(vp + 1024);                                       \
    vf11 = *(const bfrag*)(vp + 1536);                                       \
    vp += 4096;                                                              \
  } while (0)

  if (jw >= 0) {
    LOADK();                        // tile 0
    for (int j = 0; j <= jw; ++j) {
      LOADV();                      // V tile j (consumed at PV below)

      // ---- S^T subtile = K[khalf] * Q^T over hd=64
      f32x16 st;
      #pragma unroll
      for (int r = 0; r < 16; r++) st[r] = 0.f;
      __builtin_amdgcn_s_setprio(1);
      st = __builtin_amdgcn_mfma_f32_32x32x16_bf16(kA0, qf0, st, 0, 0, 0);
      st = __builtin_amdgcn_mfma_f32_32x32x16_bf16(kA1, qf1, st, 0, 0, 0);
      st = __builtin_amdgcn_mfma_f32_32x32x16_bf16(kA2, qf2, st, 0, 0, 0);
      st = __builtin_amdgcn_mfma_f32_32x32x16_bf16(kA3, qf3, st, 0, 0, 0);
      __builtin_amdgcn_s_setprio(0);

      // prefetch K tile j+1 in place (retires under softmax+PV below)
      if (j < jw) LOADK();

      // ---- causal mask (only the wave's last tile can be diagonal)
      if (j == jw) {
        const int thr = qg_lane - 64 * j - 32 * khalf - 4 * hi5;
        #pragma unroll
        for (int r = 0; r < 16; r++) {
          const int kl = (r & 3) + 8 * (r >> 2);
          st[r] = (kl > thr) ? -INFINITY : st[r];
        }
      }

      // ---- p = exp2(S) (shift-free), partial row-sum
      #pragma unroll
      for (int r = 0; r < 16; r++) st[r] = exp2f(st[r]);
      {
        float s8[8];
        #pragma unroll
        for (int r = 0; r < 8; r++) s8[r] = st[r] + st[r + 8];
        float rs = ((s8[0] + s8[4]) + (s8[1] + s8[5])) +
                   ((s8[2] + s8[6]) + (s8[3] + s8[7]));
        rs += __shfl_xor(rs, 32);
        l += rs;
      }

      // ---- O^T += V^T * P^T
      {
        unsigned pk0 = cvt_pk(st[0], st[1]);
        unsigned pk1 = cvt_pk(st[2], st[3]);
        unsigned pk2 = cvt_pk(st[4], st[5]);
        unsigned pk3 = cvt_pk(st[6], st[7]);
        plswap(pk0, pk2);
        plswap(pk1, pk3);
        union { unsigned u[4]; bfrag f; } pb;
        pb.u[0] = pk0; pb.u[1] = pk1; pb.u[2] = pk2; pb.u[3] = pk3;
        __builtin_amdgcn_s_setprio(1);
        o0 = __builtin_amdgcn_mfma_f32_32x32x16_bf16(vf00, pb.f, o0, 0, 0, 0);
        o1 = __builtin_amdgcn_mfma_f32_32x32x16_bf16(vf01, pb.f, o1, 0, 0, 0);
        __builtin_amdgcn_s_setprio(0);
        pk0 = cvt_pk(st[8], st[9]);
        pk1 = cvt_pk(st[10], st[11]);
        pk2 = cvt_pk(st[12], st[13]);
        pk3 = cvt_pk(st[14], st[15]);
        plswap(pk0, pk2);
        plswap(pk1, pk3);
        pb.u[0] = pk0; pb.u[1] = pk1; pb.u[2] = pk2; pb.u[3] = pk3;
        __builtin_amdgcn_s_setprio(1);
        o0 = __builtin_amdgcn_mfma_f32_32x32x16_bf16(vf10, pb.f, o0, 0, 0, 0);
        o1 = __builtin_amdgcn_mfma_f32_32x32x16_bf16(vf11, pb.f, o1, 0, 0, 0);
        __builtin_amdgcn_s_setprio(0);
      }
    }
  }
  #undef LOADK
  #undef LOADV

  // ---- partner-wave (khalf) reduction via LDS, stride 17 (conflict-free)
  const int moff = (qhalf * 64 + lane) * 17;
  if (khalf) {
    #pragma unroll
    for (int r = 0; r < 16; r++) smrg[moff + r] = o0[r];
    smrg[moff + 16] = l;
  }
  __syncthreads();
  if (!khalf) {
    #pragma unroll
    for (int r = 0; r < 16; r++) o0[r] += smrg[moff + r];
    l += smrg[moff + 16];
  }
  __syncthreads();
  if (khalf) {
    #pragma unroll
    for (int r = 0; r < 16; r++) smrg[moff + r] = o1[r];
  }
  __syncthreads();
  if (!khalf) {
    #pragma unroll
    for (int r = 0; r < 16; r++) o1[r] += smrg[moff + r];
    const float inv = 1.0f / l;
    unsigned short* orow = Og + ((size_t)(b * T_ + qg_lane)) * D_ + h * HD_;
    #pragma unroll
    for (int r = 0; r < 16; r += 2) {
      const int d0 = (r & 3) + 8 * (r >> 2) + 4 * hi5;
      unsigned u0 = cvt_pk(o0[r] * inv, o0[r + 1] * inv);
      unsigned u1 = cvt_pk(o1[r] * inv, o1[r + 1] * inv);
      *(unsigned*)(orow + d0)      = u0;
      *(unsigned*)(orow + 32 + d0) = u1;
    }
  }
}

// ---------------------------------------------------------------------------
extern "C" void kernel_launch(void* const* d_in, const int* in_sizes, int n_in,
                              void* d_out, int out_size, void* d_ws, size_t ws_size,
                              hipStream_t stream)
{
  const float* x  = (const float*)d_in[0];
  const float* Wq = (const float*)d_in[1];
  const float* bq = (const float*)d_in[2];
  const float* Wk = (const float*)d_in[3];
  const float* bk = (const float*)d_in[4];
  const float* Wv = (const float*)d_in[5];
  const float* bv = (const float*)d_in[6];
  const float* Wo = (const float*)d_in[7];
  const float* bo = (const float*)d_in[8];

  unsigned short* ws  = (unsigned short*)d_ws;
  unsigned short* xb  = ws;
  unsigned short* wqb = xb  + (size_t)M_ * D_;     // wq|wk|wv contiguous
  unsigned short* wkb = wqb + (size_t)D_ * D_;
  unsigned short* wvb = wkb + (size_t)D_ * D_;
  unsigned short* wob = wvb + (size_t)D_ * D_;
  unsigned short* Qb  = wob + (size_t)D_ * D_;
  unsigned short* Kb  = Qb  + (size_t)M_ * D_;     // fragment-major
  unsigned short* Vtb = Kb  + (size_t)M_ * D_;     // fragment-major
  unsigned short* AOb = Vtb + (size_t)M_ * D_;

  convert_all<<<2048, 256, 0, stream>>>(x, Wq, Wk, Wv, Wo, xb);

  const float qscale = 0.125f * 1.44269504f;   // 1/sqrt(64) * log2(e)
  dim3 gq(M_ / 128, 3072 / 128);
  gemm_qkv<<<gq, 256, 0, stream>>>(xb, wqb, bq, bk, bv, Qb, Kb, Vtb, qscale);

  attn_kernel<<<2048, 256, 0, stream>>>(Qb, Kb, Vtb, AOb);

  dim3 go(M_ / 128, D_ / 128);
  gemm_out<<<go, 256, 0, stream>>>(AOb, wob, bo, (float*)d_out, M_, D_, D_);
}